// Round 1
// baseline (626.739 us; speedup 1.0000x reference)
//
#include <hip/hip_runtime.h>
#include <hip/hip_bf16.h>

#define BATCH 64
#define SEQ   256
#define EMB   64
#define QKVD  64
#define KD    8192      // L*EMB
#define ND    8192      // L*QKV
#define SEQD  16384     // SEQ*EMB (per-batch x row)

typedef __attribute__((ext_vector_type(8))) short bf16x8;
typedef __attribute__((ext_vector_type(4))) float f32x4;

struct WArgs { const float* W[6]; const float* b[6]; };

// branchless round-to-nearest-even fp32 -> bf16 bits (inputs are finite)
__device__ __forceinline__ short f2bf(float f) {
    unsigned u = __builtin_bit_cast(unsigned, f);
    u += 0x7fffu + ((u >> 16) & 1u);
    return (short)(u >> 16);
}

// ---------------- kernel 1: x fp32 -> bf16 (1,048,576 elems, exact grid) ----
__global__ __launch_bounds__(256)
void cvt_x_kernel(const float* __restrict__ x, short* __restrict__ xb) {
    const int i = (blockIdx.x * 256 + threadIdx.x) * 4;
    float4 v = *reinterpret_cast<const float4*>(x + i);
    short4 o;
    o.x = f2bf(v.x); o.y = f2bf(v.y); o.z = f2bf(v.z); o.w = f2bf(v.w);
    *reinterpret_cast<short4*>(xb + i) = o;
}

// ---------------- kernel 2: QKV projections --------------------------------
// out[gi][m][n] = sum_k xs[m,k] * W[n,k] + bias[n]
// grid = (128 n-tiles, 6 gemms), block = 256 (4 waves), wave tile = 64m x 16n
__global__ __launch_bounds__(256)
void qkv_gemm_kernel(const short* __restrict__ xb, WArgs wa,
                     float* __restrict__ qkv) {
    const int gi   = blockIdx.y;          // g*3 + {Q,K,V}
    const int g    = gi / 3;
    const int wave = threadIdx.x >> 6;
    const int lane = threadIdx.x & 63;
    const int r    = lane & 15;           // A row / B col / D col within frag
    const int kb   = lane >> 4;           // k sub-block (8 elems each)
    const int nbr  = blockIdx.x * 64 + wave * 16 + r;   // global n for this lane

    const float* __restrict__ wp = wa.W[gi] + (size_t)nbr * KD + kb * 8;
    const short* a0p = xb + (size_t)r * SEQD + g * KD + kb * 8;
    const short* a1p = a0p + 16 * SEQD;
    const short* a2p = a0p + 32 * SEQD;
    const short* a3p = a0p + 48 * SEQD;

    f32x4 acc0 = {0.f, 0.f, 0.f, 0.f};
    f32x4 acc1 = acc0, acc2 = acc0, acc3 = acc0;

    // prefetch k-step 0
    bf16x8 a0 = *(const bf16x8*)a0p;
    bf16x8 a1 = *(const bf16x8*)a1p;
    bf16x8 a2 = *(const bf16x8*)a2p;
    bf16x8 a3 = *(const bf16x8*)a3p;
    float4 w0 = *(const float4*)wp;
    float4 w1 = *(const float4*)(wp + 4);

    for (int ks = 0; ks < KD / 32 - 1; ++ks) {
        const int off = (ks + 1) * 32;
        // issue next-step loads (HBM latency hides under cvt+MFMA)
        bf16x8 na0 = *(const bf16x8*)(a0p + off);
        bf16x8 na1 = *(const bf16x8*)(a1p + off);
        bf16x8 na2 = *(const bf16x8*)(a2p + off);
        bf16x8 na3 = *(const bf16x8*)(a3p + off);
        float4 nw0 = *(const float4*)(wp + off);
        float4 nw1 = *(const float4*)(wp + off + 4);

        bf16x8 bb;
        bb[0] = f2bf(w0.x); bb[1] = f2bf(w0.y); bb[2] = f2bf(w0.z); bb[3] = f2bf(w0.w);
        bb[4] = f2bf(w1.x); bb[5] = f2bf(w1.y); bb[6] = f2bf(w1.z); bb[7] = f2bf(w1.w);
        acc0 = __builtin_amdgcn_mfma_f32_16x16x32_bf16(a0, bb, acc0, 0, 0, 0);
        acc1 = __builtin_amdgcn_mfma_f32_16x16x32_bf16(a1, bb, acc1, 0, 0, 0);
        acc2 = __builtin_amdgcn_mfma_f32_16x16x32_bf16(a2, bb, acc2, 0, 0, 0);
        acc3 = __builtin_amdgcn_mfma_f32_16x16x32_bf16(a3, bb, acc3, 0, 0, 0);

        a0 = na0; a1 = na1; a2 = na2; a3 = na3; w0 = nw0; w1 = nw1;
    }
    {   // tail k-step
        bf16x8 bb;
        bb[0] = f2bf(w0.x); bb[1] = f2bf(w0.y); bb[2] = f2bf(w0.z); bb[3] = f2bf(w0.w);
        bb[4] = f2bf(w1.x); bb[5] = f2bf(w1.y); bb[6] = f2bf(w1.z); bb[7] = f2bf(w1.w);
        acc0 = __builtin_amdgcn_mfma_f32_16x16x32_bf16(a0, bb, acc0, 0, 0, 0);
        acc1 = __builtin_amdgcn_mfma_f32_16x16x32_bf16(a1, bb, acc1, 0, 0, 0);
        acc2 = __builtin_amdgcn_mfma_f32_16x16x32_bf16(a2, bb, acc2, 0, 0, 0);
        acc3 = __builtin_amdgcn_mfma_f32_16x16x32_bf16(a3, bb, acc3, 0, 0, 0);
    }

    // D layout (m89): col = lane&15, row = (lane>>4)*4 + reg
    const float bias = wa.b[gi][nbr];
    float* orow = qkv + (size_t)gi * (BATCH * ND) + nbr;
    #pragma unroll
    for (int reg = 0; reg < 4; ++reg) {
        const int m = kb * 4 + reg;
        orow[(size_t)(m)      * ND] = acc0[reg] + bias;
        orow[(size_t)(m + 16) * ND] = acc1[reg] + bias;
        orow[(size_t)(m + 32) * ND] = acc2[reg] + bias;
        orow[(size_t)(m + 48) * ND] = acc3[reg] + bias;
    }
}

// ---------------- kernel 3: attention per (batch, group) -------------------
// scores[i][j] = Q[i,:]·K[j,:]; softmax over i (query axis); Z = attn·V; ×0.125
__global__ __launch_bounds__(256)
void attn_kernel(const float* __restrict__ qkv, float* __restrict__ out) {
    __shared__ float Ql[128 * 65];   // Q, then reused for V
    __shared__ float Kl[128 * 65];
    __shared__ float Sc[128 * 129];
    __shared__ float Pm[256];
    __shared__ float Ps[256];
    __shared__ float Rden[128];

    const int b = blockIdx.x;
    const int g = blockIdx.y;
    const int t = threadIdx.x;

    const float* __restrict__ Qg = qkv + ((size_t)(3 * g + 0) * BATCH + b) * ND;
    const float* __restrict__ Kg = qkv + ((size_t)(3 * g + 1) * BATCH + b) * ND;
    const float* __restrict__ Vg = qkv + ((size_t)(3 * g + 2) * BATCH + b) * ND;

    for (int e = t; e < 8192; e += 256) {
        const int i = e >> 6, k = e & 63;
        Ql[i * 65 + k] = Qg[e];
        Kl[i * 65 + k] = Kg[e];
    }
    __syncthreads();

    // scores: 8x8 register tile per thread
    {
        const int i0 = (t >> 4) * 8;
        const int j0 = (t & 15) * 8;
        float s[8][8];
        #pragma unroll
        for (int rr = 0; rr < 8; ++rr)
            #pragma unroll
            for (int cc = 0; cc < 8; ++cc) s[rr][cc] = 0.f;
        for (int k = 0; k < 64; ++k) {
            float qv[8], kv[8];
            #pragma unroll
            for (int rr = 0; rr < 8; ++rr) qv[rr] = Ql[(i0 + rr) * 65 + k];
            #pragma unroll
            for (int cc = 0; cc < 8; ++cc) kv[cc] = Kl[(j0 + cc) * 65 + k];
            #pragma unroll
            for (int rr = 0; rr < 8; ++rr)
                #pragma unroll
                for (int cc = 0; cc < 8; ++cc)
                    s[rr][cc] = fmaf(qv[rr], kv[cc], s[rr][cc]);
        }
        #pragma unroll
        for (int rr = 0; rr < 8; ++rr)
            #pragma unroll
            for (int cc = 0; cc < 8; ++cc)
                Sc[(i0 + rr) * 129 + (j0 + cc)] = s[rr][cc];
    }
    __syncthreads();

    // V fill (Q dead) + per-column partial max; column j, half h
    const int j = t & 127, h = t >> 7;
    {
        for (int e = t; e < 8192; e += 256) {
            const int i = e >> 6, k = e & 63;
            Ql[i * 65 + k] = Vg[e];
        }
        float m = -3.0e38f;
        for (int i = h * 64; i < h * 64 + 64; ++i)
            m = fmaxf(m, Sc[i * 129 + j]);
        Pm[h * 128 + j] = m;
    }
    __syncthreads();
    {
        const float m = fmaxf(Pm[j], Pm[128 + j]);
        float sum = 0.f;
        for (int i = h * 64; i < h * 64 + 64; ++i) {
            const float e = __expf(Sc[i * 129 + j] - m);
            Sc[i * 129 + j] = e;
            sum += e;
        }
        Ps[h * 128 + j] = sum;
    }
    __syncthreads();
    if (t < 128) Rden[t] = 1.0f / (Ps[t] + Ps[128 + t]);
    __syncthreads();

    // PV: 8 rows x 4 cols per thread
    {
        const int i0 = (t >> 4) * 8;
        const int k0 = (t & 15) * 4;
        float z[8][4];
        #pragma unroll
        for (int rr = 0; rr < 8; ++rr)
            #pragma unroll
            for (int cc = 0; cc < 4; ++cc) z[rr][cc] = 0.f;
        for (int jj = 0; jj < 128; ++jj) {
            const float rd = Rden[jj];
            float av[8], vv[4];
            #pragma unroll
            for (int rr = 0; rr < 8; ++rr) av[rr] = Sc[(i0 + rr) * 129 + jj] * rd;
            #pragma unroll
            for (int cc = 0; cc < 4; ++cc) vv[cc] = Ql[jj * 65 + k0 + cc];
            #pragma unroll
            for (int rr = 0; rr < 8; ++rr)
                #pragma unroll
                for (int cc = 0; cc < 4; ++cc)
                    z[rr][cc] = fmaf(av[rr], vv[cc], z[rr][cc]);
        }
        float* op = out + (size_t)b * (SEQ * QKVD) + (size_t)(g * 128) * QKVD + k0;
        #pragma unroll
        for (int rr = 0; rr < 8; ++rr) {
            float4 o;
            o.x = z[rr][0] * 0.125f; o.y = z[rr][1] * 0.125f;
            o.z = z[rr][2] * 0.125f; o.w = z[rr][3] * 0.125f;
            *reinterpret_cast<float4*>(op + (size_t)(i0 + rr) * QKVD) = o;
        }
    }
}

// ---------------- launcher --------------------------------------------------
extern "C" void kernel_launch(void* const* d_in, const int* in_sizes, int n_in,
                              void* d_out, int out_size, void* d_ws, size_t ws_size,
                              hipStream_t stream) {
    const float* x = (const float*)d_in[0];
    WArgs wa;
    for (int g = 0; g < 2; ++g)
        for (int q = 0; q < 3; ++q) {
            wa.W[g * 3 + q] = (const float*)d_in[1 + g * 6 + q * 2];
            wa.b[g * 3 + q] = (const float*)d_in[2 + g * 6 + q * 2];
        }

    short* xb  = (short*)d_ws;                                  // 2 MiB bf16 x
    float* qkv = (float*)((char*)d_ws + (size_t)2 * 1024 * 1024); // 12 MiB QKV

    cvt_x_kernel<<<dim3(1024), dim3(256), 0, stream>>>(x, xb);
    qkv_gemm_kernel<<<dim3(ND / 64, 6), dim3(256), 0, stream>>>(xb, wa, qkv);
    attn_kernel<<<dim3(BATCH, 2), dim3(256), 0, stream>>>(qkv, (float*)d_out);
}

// Round 2
// 568.740 us; speedup vs baseline: 1.1020x; 1.1020x over previous
//
#include <hip/hip_runtime.h>
#include <hip/hip_bf16.h>

#define BATCH 64
#define SEQ   256
#define EMB   64
#define QKVD  64
#define KD    8192      // L*EMB
#define ND    8192      // L*QKV
#define SEQD  16384     // SEQ*EMB (per-batch x row)
#define KSPLIT 2
#define KHALF (KD / KSPLIT)          // 4096
#define NSTEP (KHALF / 32)           // 128 k-steps of 32

typedef __attribute__((ext_vector_type(8))) short bf16x8;
typedef __attribute__((ext_vector_type(4))) float f32x4;

struct WArgs { const float* W[6]; const float* b[6]; };

// branchless round-to-nearest-even fp32 -> bf16 bits (inputs are finite)
__device__ __forceinline__ short f2bf(float f) {
    unsigned u = __builtin_bit_cast(unsigned, f);
    u += 0x7fffu + ((u >> 16) & 1u);
    return (short)(u >> 16);
}

// ---------------- kernel 1: x fp32 -> bf16 ----------------------------------
__global__ __launch_bounds__(256)
void cvt_x_kernel(const float* __restrict__ x, short* __restrict__ xb) {
    const int i = (blockIdx.x * 256 + threadIdx.x) * 4;
    float4 v = *reinterpret_cast<const float4*>(x + i);
    short4 o;
    o.x = f2bf(v.x); o.y = f2bf(v.y); o.z = f2bf(v.z); o.w = f2bf(v.w);
    *reinterpret_cast<short4*>(xb + i) = o;
}

// ---------------- kernel 2: QKV projections ---------------------------------
// out[gi][m][n] = sum_k xs[m,k] * W[n,k] (+ bias in kz==0 half)
// grid = (128 n-tiles, 6 gemms, 2 k-halves), block = 256 (4 waves)
// wave tile = 64m x 16n; explicit 2-deep register prefetch pipeline.

struct Frag {
    bf16x8 a0, a1, a2, a3;   // A rows r, r+16, r+32, r+48 (16B each)
    float4 w0, w1;           // W row nbr, 8 fp32
};

__device__ __forceinline__ Frag ldfrag(const short* __restrict__ ap,
                                       const float* __restrict__ wp, int koff) {
    Frag f;
    f.a0 = *(const bf16x8*)(ap + koff);
    f.a1 = *(const bf16x8*)(ap + koff + 16 * SEQD);
    f.a2 = *(const bf16x8*)(ap + koff + 32 * SEQD);
    f.a3 = *(const bf16x8*)(ap + koff + 48 * SEQD);
    f.w0 = *(const float4*)(wp + koff);
    f.w1 = *(const float4*)(wp + koff + 4);
    return f;
}

__device__ __forceinline__ void comp(const Frag& f, f32x4& c0, f32x4& c1,
                                     f32x4& c2, f32x4& c3) {
    bf16x8 bb;
    bb[0] = f2bf(f.w0.x); bb[1] = f2bf(f.w0.y); bb[2] = f2bf(f.w0.z); bb[3] = f2bf(f.w0.w);
    bb[4] = f2bf(f.w1.x); bb[5] = f2bf(f.w1.y); bb[6] = f2bf(f.w1.z); bb[7] = f2bf(f.w1.w);
    c0 = __builtin_amdgcn_mfma_f32_16x16x32_bf16(f.a0, bb, c0, 0, 0, 0);
    c1 = __builtin_amdgcn_mfma_f32_16x16x32_bf16(f.a1, bb, c1, 0, 0, 0);
    c2 = __builtin_amdgcn_mfma_f32_16x16x32_bf16(f.a2, bb, c2, 0, 0, 0);
    c3 = __builtin_amdgcn_mfma_f32_16x16x32_bf16(f.a3, bb, c3, 0, 0, 0);
}

__global__ __launch_bounds__(256, 4)
void qkv_gemm_kernel(const short* __restrict__ xb, WArgs wa,
                     float* __restrict__ qkv0, float* __restrict__ qkv1) {
    const int gi   = blockIdx.y;          // g*3 + {Q,K,V}
    const int g    = gi / 3;
    const int kz   = blockIdx.z;          // K half
    const int wave = threadIdx.x >> 6;
    const int lane = threadIdx.x & 63;
    const int r    = lane & 15;           // A row / B col within frag
    const int kb   = lane >> 4;           // k sub-block (8 elems)
    const int nbr  = blockIdx.x * 64 + wave * 16 + r;

    const float* __restrict__ wp = wa.W[gi] + (size_t)nbr * KD + kz * KHALF + kb * 8;
    const short* __restrict__ ap = xb + (size_t)r * SEQD + g * KD + kz * KHALF + kb * 8;

    f32x4 acc0 = {0.f, 0.f, 0.f, 0.f};
    f32x4 acc1 = acc0, acc2 = acc0, acc3 = acc0;

    Frag f0 = ldfrag(ap, wp, 0);
    Frag f1 = ldfrag(ap, wp, 32);

    #pragma unroll 2
    for (int ks = 0; ks + 2 < NSTEP; ks += 2) {
        Frag n0 = ldfrag(ap, wp, (ks + 2) * 32);
        comp(f0, acc0, acc1, acc2, acc3);
        f0 = n0;
        Frag n1 = ldfrag(ap, wp, (ks + 3) * 32);
        comp(f1, acc0, acc1, acc2, acc3);
        f1 = n1;
    }
    comp(f0, acc0, acc1, acc2, acc3);
    comp(f1, acc0, acc1, acc2, acc3);

    // D layout (m89): col = lane&15, row = (lane>>4)*4 + reg
    const float bias = (kz == 0) ? wa.b[gi][nbr] : 0.0f;
    float* __restrict__ qkv = (kz == 0) ? qkv0 : qkv1;
    float* orow = qkv + (size_t)gi * (BATCH * ND) + nbr;
    #pragma unroll
    for (int reg = 0; reg < 4; ++reg) {
        const int m = kb * 4 + reg;
        orow[(size_t)(m)      * ND] = acc0[reg] + bias;
        orow[(size_t)(m + 16) * ND] = acc1[reg] + bias;
        orow[(size_t)(m + 32) * ND] = acc2[reg] + bias;
        orow[(size_t)(m + 48) * ND] = acc3[reg] + bias;
    }
}

// ---------------- kernel 3: attention per (batch, group) -------------------
// scores[i][j] = Q[i,:]·K[j,:]; softmax over i (query axis); Z = attn·V; ×0.125
__global__ __launch_bounds__(256)
void attn_kernel(const float* __restrict__ qkv0, const float* __restrict__ qkv1,
                 float* __restrict__ out) {
    __shared__ float Ql[128 * 65];   // Q, then reused for V
    __shared__ float Kl[128 * 65];
    __shared__ float Sc[128 * 129];
    __shared__ float Pm[256];
    __shared__ float Ps[256];
    __shared__ float Rden[128];

    const int b = blockIdx.x;
    const int g = blockIdx.y;
    const int t = threadIdx.x;

    const size_t qoff = ((size_t)(3 * g + 0) * BATCH + b) * ND;
    const size_t koff = ((size_t)(3 * g + 1) * BATCH + b) * ND;
    const size_t voff = ((size_t)(3 * g + 2) * BATCH + b) * ND;

    for (int e = t; e < 8192; e += 256) {
        const int i = e >> 6, k = e & 63;
        Ql[i * 65 + k] = qkv0[qoff + e] + qkv1[qoff + e];
        Kl[i * 65 + k] = qkv0[koff + e] + qkv1[koff + e];
    }
    __syncthreads();

    // scores: 8x8 register tile per thread
    {
        const int i0 = (t >> 4) * 8;
        const int j0 = (t & 15) * 8;
        float s[8][8];
        #pragma unroll
        for (int rr = 0; rr < 8; ++rr)
            #pragma unroll
            for (int cc = 0; cc < 8; ++cc) s[rr][cc] = 0.f;
        for (int k = 0; k < 64; ++k) {
            float qv[8], kv[8];
            #pragma unroll
            for (int rr = 0; rr < 8; ++rr) qv[rr] = Ql[(i0 + rr) * 65 + k];
            #pragma unroll
            for (int cc = 0; cc < 8; ++cc) kv[cc] = Kl[(j0 + cc) * 65 + k];
            #pragma unroll
            for (int rr = 0; rr < 8; ++rr)
                #pragma unroll
                for (int cc = 0; cc < 8; ++cc)
                    s[rr][cc] = fmaf(qv[rr], kv[cc], s[rr][cc]);
        }
        #pragma unroll
        for (int rr = 0; rr < 8; ++rr)
            #pragma unroll
            for (int cc = 0; cc < 8; ++cc)
                Sc[(i0 + rr) * 129 + (j0 + cc)] = s[rr][cc];
    }
    __syncthreads();

    // V fill (Q dead) + per-column partial max; column j, half h
    const int j = t & 127, h = t >> 7;
    {
        for (int e = t; e < 8192; e += 256) {
            const int i = e >> 6, k = e & 63;
            Ql[i * 65 + k] = qkv0[voff + e] + qkv1[voff + e];
        }
        float m = -3.0e38f;
        for (int i = h * 64; i < h * 64 + 64; ++i)
            m = fmaxf(m, Sc[i * 129 + j]);
        Pm[h * 128 + j] = m;
    }
    __syncthreads();
    {
        const float m = fmaxf(Pm[j], Pm[128 + j]);
        float sum = 0.f;
        for (int i = h * 64; i < h * 64 + 64; ++i) {
            const float e = __expf(Sc[i * 129 + j] - m);
            Sc[i * 129 + j] = e;
            sum += e;
        }
        Ps[h * 128 + j] = sum;
    }
    __syncthreads();
    if (t < 128) Rden[t] = 1.0f / (Ps[t] + Ps[128 + t]);
    __syncthreads();

    // PV: 8 rows x 4 cols per thread
    {
        const int i0 = (t >> 4) * 8;
        const int k0 = (t & 15) * 4;
        float z[8][4];
        #pragma unroll
        for (int rr = 0; rr < 8; ++rr)
            #pragma unroll
            for (int cc = 0; cc < 4; ++cc) z[rr][cc] = 0.f;
        for (int jj = 0; jj < 128; ++jj) {
            const float rd = Rden[jj];
            float av[8], vv[4];
            #pragma unroll
            for (int rr = 0; rr < 8; ++rr) av[rr] = Sc[(i0 + rr) * 129 + jj] * rd;
            #pragma unroll
            for (int cc = 0; cc < 4; ++cc) vv[cc] = Ql[jj * 65 + k0 + cc];
            #pragma unroll
            for (int rr = 0; rr < 8; ++rr)
                #pragma unroll
                for (int cc = 0; cc < 4; ++cc)
                    z[rr][cc] = fmaf(av[rr], vv[cc], z[rr][cc]);
        }
        float* op = out + (size_t)b * (SEQ * QKVD) + (size_t)(g * 128) * QKVD + k0;
        #pragma unroll
        for (int rr = 0; rr < 8; ++rr) {
            float4 o;
            o.x = z[rr][0] * 0.125f; o.y = z[rr][1] * 0.125f;
            o.z = z[rr][2] * 0.125f; o.w = z[rr][3] * 0.125f;
            *reinterpret_cast<float4*>(op + (size_t)(i0 + rr) * QKVD) = o;
        }
    }
}

// ---------------- launcher --------------------------------------------------
extern "C" void kernel_launch(void* const* d_in, const int* in_sizes, int n_in,
                              void* d_out, int out_size, void* d_ws, size_t ws_size,
                              hipStream_t stream) {
    const float* x = (const float*)d_in[0];
    WArgs wa;
    for (int g = 0; g < 2; ++g)
        for (int q = 0; q < 3; ++q) {
            wa.W[g * 3 + q] = (const float*)d_in[1 + g * 6 + q * 2];
            wa.b[g * 3 + q] = (const float*)d_in[2 + g * 6 + q * 2];
        }

    short* xb   = (short*)d_ws;                                     // 2 MiB
    float* qkvA = (float*)((char*)d_ws + (size_t)4  * 1024 * 1024); // 12.6 MiB
    float* qkvB = (float*)((char*)d_ws + (size_t)20 * 1024 * 1024); // 12.6 MiB

    cvt_x_kernel<<<dim3(1024), dim3(256), 0, stream>>>(x, xb);
    qkv_gemm_kernel<<<dim3(ND / 64, 6, KSPLIT), dim3(256), 0, stream>>>(xb, wa, qkvA, qkvB);
    attn_kernel<<<dim3(BATCH, 2), dim3(256), 0, stream>>>(qkvA, qkvB, (float*)d_out);
}

// Round 3
// 358.727 us; speedup vs baseline: 1.7471x; 1.5854x over previous
//
#include <hip/hip_runtime.h>
#include <hip/hip_bf16.h>

#define BATCH 64
#define SEQ   256
#define EMB   64
#define QKVD  64
#define KD    8192      // L*EMB
#define ND    8192      // L*QKV
#define SEQD  16384     // SEQ*EMB (per-batch x row)
#define BK    64
#define NCHUNK (KD / BK)   // 128

typedef __attribute__((ext_vector_type(8))) short bf16x8;
typedef __attribute__((ext_vector_type(4))) float f32x4;

struct WArgs { const float* W[6]; const float* b[6]; };

// branchless round-to-nearest-even fp32 -> bf16 bits (inputs are finite)
__device__ __forceinline__ short f2bf(float f) {
    unsigned u = __builtin_bit_cast(unsigned, f);
    u += 0x7fffu + ((u >> 16) & 1u);
    return (short)(u >> 16);
}

// async global->LDS, 16B per lane; LDS dest = wave-uniform base + lane*16
__device__ __forceinline__ void gl16(const void* g, void* l) {
    __builtin_amdgcn_global_load_lds(
        (const __attribute__((address_space(1))) void*)g,
        (__attribute__((address_space(3))) void*)l, 16, 0, 0);
}

// ---------------- kernel 1: x fp32 -> bf16 ----------------------------------
__global__ __launch_bounds__(256)
void cvt_x_kernel(const float* __restrict__ x, short* __restrict__ xb) {
    const int i = (blockIdx.x * 256 + threadIdx.x) * 4;
    float4 v = *reinterpret_cast<const float4*>(x + i);
    short4 o;
    o.x = f2bf(v.x); o.y = f2bf(v.y); o.z = f2bf(v.z); o.w = f2bf(v.w);
    *reinterpret_cast<short4*>(xb + i) = o;
}

// ---------------- kernel 2: QKV projections ---------------------------------
// C[m][n] = sum_k xs[m,k] * W[n,k] + b[n], per gi in [0,6)
// block: 64m x 64n tile, BK=64 k-chunks, 4 waves (wave tile 64m x 16n)
// 2-phase: STAGE(t+1) via global_load_lds (no reg dest -> uncollapsible),
// COMPUTE(t) from LDS, one barrier-drain per chunk.
__global__ __launch_bounds__(256, 3)
void qkv_gemm_kernel(const short* __restrict__ xb, WArgs wa,
                     float* __restrict__ qkv) {
    __shared__ __attribute__((aligned(16))) short A_lds[2][64 * 64]; // 2x8KB bf16
    __shared__ __attribute__((aligned(16))) float W_lds[2][64 * 64]; // 2x16KB f32

    const int gi = blockIdx.y;
    const int g  = gi / 3;
    const int wv = threadIdx.x >> 6;
    const int ln = threadIdx.x & 63;
    const int r  = ln & 15;           // n within wave tile / frag index
    const int kb = ln >> 4;           // k sub-block (8 elems)
    const int n0 = blockIdx.x * 64;

    const float* __restrict__ Wg = wa.W[gi];

    // staging lane constants (source pre-swizzle: chunk ^= row&7, rule #21)
    const int a_m = ln >> 3;                 // A row within 8-row issue
    const int a_c = (ln & 7) ^ (ln >> 3);    // A swizzled 16B-chunk (3 bits)
    const int w_r = ln >> 4;                 // W row within 4-row issue

    f32x4 acc0 = {0.f, 0.f, 0.f, 0.f};
    f32x4 acc1 = acc0, acc2 = acc0, acc3 = acc0;

    auto stage = [&](int t, int buf) {
        const short* As = xb + g * KD + t * BK;
        #pragma unroll
        for (int ii = 0; ii < 2; ++ii) {              // 2 x 1KB A issues/wave
            const int i = wv * 2 + ii;                // 8 rows each
            const short* src = As + (size_t)(i * 8 + a_m) * SEQD + a_c * 8;
            gl16(src, (char*)&A_lds[buf][0] + i * 1024);
        }
        const float* Ws = Wg + (size_t)n0 * KD + t * BK;
        #pragma unroll
        for (int jj = 0; jj < 4; ++jj) {              // 4 x 1KB W issues/wave
            const int j = wv * 4 + jj;                // 4 rows each
            const int nrow = j * 4 + w_r;
            const int c = (ln & 15) ^ (nrow & 7);     // swizzled 16B-chunk
            const float* src = Ws + (size_t)nrow * KD + c * 4;
            gl16(src, (char*)&W_lds[buf][0] + j * 1024);
        }
    };

    auto compute = [&](int buf) {
        const short* Ab = &A_lds[buf][0];
        const float* Wb = &W_lds[buf][0];
        const int wrow = wv * 16 + r;
        #pragma unroll
        for (int kk = 0; kk < 2; ++kk) {
            const int c0 = kk * 8 + kb * 2;
            f32x4 w0 = *(const f32x4*)(Wb + wrow * 64 + ((c0       ^ (r & 7)) * 4));
            f32x4 w1 = *(const f32x4*)(Wb + wrow * 64 + (((c0 + 1) ^ (r & 7)) * 4));
            bf16x8 bb;
            bb[0] = f2bf(w0[0]); bb[1] = f2bf(w0[1]); bb[2] = f2bf(w0[2]); bb[3] = f2bf(w0[3]);
            bb[4] = f2bf(w1[0]); bb[5] = f2bf(w1[1]); bb[6] = f2bf(w1[2]); bb[7] = f2bf(w1[3]);
            const int ac = ((kk * 4 + kb) ^ (r & 7)) * 8;
            const bf16x8 a0 = *(const bf16x8*)(Ab + (0 * 16 + r) * 64 + ac);
            const bf16x8 a1 = *(const bf16x8*)(Ab + (1 * 16 + r) * 64 + ac);
            const bf16x8 a2 = *(const bf16x8*)(Ab + (2 * 16 + r) * 64 + ac);
            const bf16x8 a3 = *(const bf16x8*)(Ab + (3 * 16 + r) * 64 + ac);
            acc0 = __builtin_amdgcn_mfma_f32_16x16x32_bf16(a0, bb, acc0, 0, 0, 0);
            acc1 = __builtin_amdgcn_mfma_f32_16x16x32_bf16(a1, bb, acc1, 0, 0, 0);
            acc2 = __builtin_amdgcn_mfma_f32_16x16x32_bf16(a2, bb, acc2, 0, 0, 0);
            acc3 = __builtin_amdgcn_mfma_f32_16x16x32_bf16(a3, bb, acc3, 0, 0, 0);
        }
    };

    stage(0, 0);
    __syncthreads();
    for (int t = 0; t < NCHUNK - 1; ++t) {
        stage(t + 1, (t + 1) & 1);   // issue next chunk BEFORE compute
        compute(t & 1);
        __syncthreads();             // drains vmcnt+lgkmcnt (compiler-emitted)
    }
    compute((NCHUNK - 1) & 1);

    // D layout (m89): col = lane&15, row = (lane>>4)*4 + reg
    const int nbr = n0 + wv * 16 + r;
    const float bias = wa.b[gi][nbr];
    float* orow = qkv + (size_t)gi * (BATCH * ND) + nbr;
    #pragma unroll
    for (int reg = 0; reg < 4; ++reg) {
        const int m = kb * 4 + reg;
        orow[(size_t)(m)      * ND] = acc0[reg] + bias;
        orow[(size_t)(m + 16) * ND] = acc1[reg] + bias;
        orow[(size_t)(m + 32) * ND] = acc2[reg] + bias;
        orow[(size_t)(m + 48) * ND] = acc3[reg] + bias;
    }
}

// ---------------- kernel 3: attention per (batch, group) -------------------
// scores[i][j] = Q[i,:]·K[j,:]; softmax over i (query axis); Z = attn·V; ×0.125
__global__ __launch_bounds__(256)
void attn_kernel(const float* __restrict__ qkv, float* __restrict__ out) {
    __shared__ float Ql[128 * 65];   // Q, then reused for V
    __shared__ float Kl[128 * 65];
    __shared__ float Sc[128 * 129];
    __shared__ float Pm[256];
    __shared__ float Ps[256];
    __shared__ float Rden[128];

    const int b = blockIdx.x;
    const int g = blockIdx.y;
    const int t = threadIdx.x;

    const float* __restrict__ Qg = qkv + ((size_t)(3 * g + 0) * BATCH + b) * ND;
    const float* __restrict__ Kg = qkv + ((size_t)(3 * g + 1) * BATCH + b) * ND;
    const float* __restrict__ Vg = qkv + ((size_t)(3 * g + 2) * BATCH + b) * ND;

    for (int e = t; e < 8192; e += 256) {
        const int i = e >> 6, k = e & 63;
        Ql[i * 65 + k] = Qg[e];
        Kl[i * 65 + k] = Kg[e];
    }
    __syncthreads();

    // scores: 8x8 register tile per thread
    {
        const int i0 = (t >> 4) * 8;
        const int j0 = (t & 15) * 8;
        float s[8][8];
        #pragma unroll
        for (int rr = 0; rr < 8; ++rr)
            #pragma unroll
            for (int cc = 0; cc < 8; ++cc) s[rr][cc] = 0.f;
        for (int k = 0; k < 64; ++k) {
            float qv[8], kv[8];
            #pragma unroll
            for (int rr = 0; rr < 8; ++rr) qv[rr] = Ql[(i0 + rr) * 65 + k];
            #pragma unroll
            for (int cc = 0; cc < 8; ++cc) kv[cc] = Kl[(j0 + cc) * 65 + k];
            #pragma unroll
            for (int rr = 0; rr < 8; ++rr)
                #pragma unroll
                for (int cc = 0; cc < 8; ++cc)
                    s[rr][cc] = fmaf(qv[rr], kv[cc], s[rr][cc]);
        }
        #pragma unroll
        for (int rr = 0; rr < 8; ++rr)
            #pragma unroll
            for (int cc = 0; cc < 8; ++cc)
                Sc[(i0 + rr) * 129 + (j0 + cc)] = s[rr][cc];
    }
    __syncthreads();

    // V fill (Q dead) + per-column partial max; column j, half h
    const int j = t & 127, h = t >> 7;
    {
        for (int e = t; e < 8192; e += 256) {
            const int i = e >> 6, k = e & 63;
            Ql[i * 65 + k] = Vg[e];
        }
        float m = -3.0e38f;
        for (int i = h * 64; i < h * 64 + 64; ++i)
            m = fmaxf(m, Sc[i * 129 + j]);
        Pm[h * 128 + j] = m;
    }
    __syncthreads();
    {
        const float m = fmaxf(Pm[j], Pm[128 + j]);
        float sum = 0.f;
        for (int i = h * 64; i < h * 64 + 64; ++i) {
            const float e = __expf(Sc[i * 129 + j] - m);
            Sc[i * 129 + j] = e;
            sum += e;
        }
        Ps[h * 128 + j] = sum;
    }
    __syncthreads();
    if (t < 128) Rden[t] = 1.0f / (Ps[t] + Ps[128 + t]);
    __syncthreads();

    // PV: 8 rows x 4 cols per thread
    {
        const int i0 = (t >> 4) * 8;
        const int k0 = (t & 15) * 4;
        float z[8][4];
        #pragma unroll
        for (int rr = 0; rr < 8; ++rr)
            #pragma unroll
            for (int cc = 0; cc < 4; ++cc) z[rr][cc] = 0.f;
        for (int jj = 0; jj < 128; ++jj) {
            const float rd = Rden[jj];
            float av[8], vv[4];
            #pragma unroll
            for (int rr = 0; rr < 8; ++rr) av[rr] = Sc[(i0 + rr) * 129 + jj] * rd;
            #pragma unroll
            for (int cc = 0; cc < 4; ++cc) vv[cc] = Ql[jj * 65 + k0 + cc];
            #pragma unroll
            for (int rr = 0; rr < 8; ++rr)
                #pragma unroll
                for (int cc = 0; cc < 4; ++cc)
                    z[rr][cc] = fmaf(av[rr], vv[cc], z[rr][cc]);
        }
        float* op = out + (size_t)b * (SEQ * QKVD) + (size_t)(g * 128) * QKVD + k0;
        #pragma unroll
        for (int rr = 0; rr < 8; ++rr) {
            float4 o;
            o.x = z[rr][0] * 0.125f; o.y = z[rr][1] * 0.125f;
            o.z = z[rr][2] * 0.125f; o.w = z[rr][3] * 0.125f;
            *reinterpret_cast<float4*>(op + (size_t)(i0 + rr) * QKVD) = o;
        }
    }
}

// ---------------- launcher --------------------------------------------------
extern "C" void kernel_launch(void* const* d_in, const int* in_sizes, int n_in,
                              void* d_out, int out_size, void* d_ws, size_t ws_size,
                              hipStream_t stream) {
    const float* x = (const float*)d_in[0];
    WArgs wa;
    for (int g = 0; g < 2; ++g)
        for (int q = 0; q < 3; ++q) {
            wa.W[g * 3 + q] = (const float*)d_in[1 + g * 6 + q * 2];
            wa.b[g * 3 + q] = (const float*)d_in[2 + g * 6 + q * 2];
        }

    short* xb  = (short*)d_ws;                                      // 2 MiB
    float* qkv = (float*)((char*)d_ws + (size_t)4 * 1024 * 1024);   // 12.6 MiB

    cvt_x_kernel<<<dim3(1024), dim3(256), 0, stream>>>(x, xb);
    qkv_gemm_kernel<<<dim3(ND / 64, 6), dim3(256), 0, stream>>>(xb, wa, qkv);
    attn_kernel<<<dim3(BATCH, 2), dim3(256), 0, stream>>>(qkv, (float*)d_out);
}

// Round 4
// 355.909 us; speedup vs baseline: 1.7610x; 1.0079x over previous
//
#include <hip/hip_runtime.h>
#include <hip/hip_bf16.h>

#define BATCH 64
#define SEQ   256
#define EMB   64
#define QKVD  64
#define KD    8192      // L*EMB
#define ND    8192      // L*QKV
#define SEQD  16384     // SEQ*EMB (per-batch x row)
#define BK    64
#define NCHUNK (KD / BK)   // 128

typedef __attribute__((ext_vector_type(8))) short bf16x8;
typedef __attribute__((ext_vector_type(4))) float f32x4;

struct WArgs { const float* W[6]; const float* b[6]; };

// branchless round-to-nearest-even fp32 -> bf16 bits (inputs are finite)
__device__ __forceinline__ short f2bf(float f) {
    unsigned u = __builtin_bit_cast(unsigned, f);
    u += 0x7fffu + ((u >> 16) & 1u);
    return (short)(u >> 16);
}

// async global->LDS, 16B per lane; LDS dest = wave-uniform base + lane*16
__device__ __forceinline__ void gl16(const void* g, void* l) {
    __builtin_amdgcn_global_load_lds(
        (const __attribute__((address_space(1))) void*)g,
        (__attribute__((address_space(3))) void*)l, 16, 0, 0);
}

__device__ __forceinline__ void barrier_fenced() {
    asm volatile("" ::: "memory");
    __builtin_amdgcn_s_barrier();
    asm volatile("" ::: "memory");
}

// ---------------- kernel 1: x fp32 -> bf16 ----------------------------------
__global__ __launch_bounds__(256)
void cvt_x_kernel(const float* __restrict__ x, short* __restrict__ xb) {
    const int i = (blockIdx.x * 256 + threadIdx.x) * 4;
    float4 v = *reinterpret_cast<const float4*>(x + i);
    short4 o;
    o.x = f2bf(v.x); o.y = f2bf(v.y); o.z = f2bf(v.z); o.w = f2bf(v.w);
    *reinterpret_cast<short4*>(xb + i) = o;
}

// ---------------- kernel 2: QKV projections ---------------------------------
// C[m][n] = sum_k xs[m,k] * W[n,k] + b[n], per gi in [0,6)
// block: 64m x 64n tile, BK=64 k-chunks, 4 waves (wave tile 64m x 16n)
// depth-2 pipeline with COUNTED vmcnt (T4): vmcnt(6) before s_barrier keeps
// the t+1 prefetch in flight across the barrier -> HBM queue never drains.
// XCD swizzle (T1): each XCD gets a contiguous logical range (<=2 gi values)
// so A panels stay L2-resident under streaming-W eviction.
__global__ __launch_bounds__(256, 3)
void qkv_gemm_kernel(const short* __restrict__ xb, WArgs wa,
                     float* __restrict__ qkv) {
    __shared__ __attribute__((aligned(16))) short A_lds[2][64 * 64]; // 2x8KB bf16
    __shared__ __attribute__((aligned(16))) float W_lds[2][64 * 64]; // 2x16KB f32

    // bijective XCD swizzle: 768 blocks, XCD x gets logical [x*96, x*96+96)
    const int bid     = blockIdx.x;
    const int logical = (bid & 7) * 96 + (bid >> 3);
    const int gi      = logical >> 7;          // 0..5
    const int n0      = (logical & 127) * 64;  // n-tile origin
    const int g       = gi / 3;

    const int wv = threadIdx.x >> 6;
    const int ln = threadIdx.x & 63;
    const int r  = ln & 15;           // n within wave tile / frag index
    const int kb = ln >> 4;           // k sub-block (8 elems)

    const float* __restrict__ Wg = wa.W[gi];

    // staging lane constants (source pre-swizzle: chunk ^= row&7, rule #21)
    const int a_m = ln >> 3;                 // A row within 8-row issue
    const int a_c = (ln & 7) ^ (ln >> 3);    // A swizzled 16B-chunk (3 bits)
    const int w_r = ln >> 4;                 // W row within 4-row issue

    f32x4 acc0 = {0.f, 0.f, 0.f, 0.f};
    f32x4 acc1 = acc0, acc2 = acc0, acc3 = acc0;

    auto stage = [&](int t, int buf) {
        const short* As = xb + g * KD + t * BK;
        #pragma unroll
        for (int ii = 0; ii < 2; ++ii) {              // 2 x 1KB A issues/wave
            const int i = wv * 2 + ii;                // 8 rows each
            const short* src = As + (size_t)(i * 8 + a_m) * SEQD + a_c * 8;
            gl16(src, (char*)&A_lds[buf][0] + i * 1024);
        }
        const float* Ws = Wg + (size_t)n0 * KD + t * BK;
        #pragma unroll
        for (int jj = 0; jj < 4; ++jj) {              // 4 x 1KB W issues/wave
            const int j = wv * 4 + jj;                // 4 rows each
            const int nrow = j * 4 + w_r;
            const int c = (ln & 15) ^ (nrow & 7);     // swizzled 16B-chunk
            const float* src = Ws + (size_t)nrow * KD + c * 4;
            gl16(src, (char*)&W_lds[buf][0] + j * 1024);
        }
    };

    auto compute = [&](int buf) {
        const short* Ab = &A_lds[buf][0];
        const float* Wb = &W_lds[buf][0];
        const int wrow = wv * 16 + r;
        #pragma unroll
        for (int kk = 0; kk < 2; ++kk) {
            const int c0 = kk * 8 + kb * 2;
            f32x4 w0 = *(const f32x4*)(Wb + wrow * 64 + ((c0       ^ (r & 7)) * 4));
            f32x4 w1 = *(const f32x4*)(Wb + wrow * 64 + (((c0 + 1) ^ (r & 7)) * 4));
            bf16x8 bb;
            bb[0] = f2bf(w0[0]); bb[1] = f2bf(w0[1]); bb[2] = f2bf(w0[2]); bb[3] = f2bf(w0[3]);
            bb[4] = f2bf(w1[0]); bb[5] = f2bf(w1[1]); bb[6] = f2bf(w1[2]); bb[7] = f2bf(w1[3]);
            const int ac = ((kk * 4 + kb) ^ (r & 7)) * 8;
            const bf16x8 a0 = *(const bf16x8*)(Ab + (0 * 16 + r) * 64 + ac);
            const bf16x8 a1 = *(const bf16x8*)(Ab + (1 * 16 + r) * 64 + ac);
            const bf16x8 a2 = *(const bf16x8*)(Ab + (2 * 16 + r) * 64 + ac);
            const bf16x8 a3 = *(const bf16x8*)(Ab + (3 * 16 + r) * 64 + ac);
            acc0 = __builtin_amdgcn_mfma_f32_16x16x32_bf16(a0, bb, acc0, 0, 0, 0);
            acc1 = __builtin_amdgcn_mfma_f32_16x16x32_bf16(a1, bb, acc1, 0, 0, 0);
            acc2 = __builtin_amdgcn_mfma_f32_16x16x32_bf16(a2, bb, acc2, 0, 0, 0);
            acc3 = __builtin_amdgcn_mfma_f32_16x16x32_bf16(a3, bb, acc3, 0, 0, 0);
        }
    };

    // prologue: stage tiles 0 and 1 (12 issues/wave outstanding)
    stage(0, 0);
    stage(1, 1);

    for (int t = 0; t < NCHUNK - 1; ++t) {
        // own outstanding: tiles t and t+1 (6 each). vmcnt(6) => tile t landed.
        asm volatile("s_waitcnt vmcnt(6)" ::: "memory");
        barrier_fenced();             // every wave passed its vmcnt => tile t
                                      // globally in LDS; t+1 stays in flight
        compute(t & 1);
        barrier_fenced();             // all reads of buf done before overwrite
        if (t + 2 < NCHUNK) stage(t + 2, t & 1);
    }
    asm volatile("s_waitcnt vmcnt(0)" ::: "memory");
    barrier_fenced();
    compute((NCHUNK - 1) & 1);

    // D layout (m89): col = lane&15, row = (lane>>4)*4 + reg
    const int nbr = n0 + wv * 16 + r;
    const float bias = wa.b[gi][nbr];
    float* orow = qkv + (size_t)gi * (BATCH * ND) + nbr;
    #pragma unroll
    for (int reg = 0; reg < 4; ++reg) {
        const int m = kb * 4 + reg;
        orow[(size_t)(m)      * ND] = acc0[reg] + bias;
        orow[(size_t)(m + 16) * ND] = acc1[reg] + bias;
        orow[(size_t)(m + 32) * ND] = acc2[reg] + bias;
        orow[(size_t)(m + 48) * ND] = acc3[reg] + bias;
    }
}

// ---------------- kernel 3: attention per (batch, group) -------------------
// scores[i][j] = Q[i,:]·K[j,:]; softmax over i (query axis); Z = attn·V; ×0.125
__global__ __launch_bounds__(256)
void attn_kernel(const float* __restrict__ qkv, float* __restrict__ out) {
    __shared__ float Ql[128 * 65];   // Q, then reused for V
    __shared__ float Kl[128 * 65];
    __shared__ float Sc[128 * 129];
    __shared__ float Pm[256];
    __shared__ float Ps[256];
    __shared__ float Rden[128];

    const int b = blockIdx.x;
    const int g = blockIdx.y;
    const int t = threadIdx.x;

    const float* __restrict__ Qg = qkv + ((size_t)(3 * g + 0) * BATCH + b) * ND;
    const float* __restrict__ Kg = qkv + ((size_t)(3 * g + 1) * BATCH + b) * ND;
    const float* __restrict__ Vg = qkv + ((size_t)(3 * g + 2) * BATCH + b) * ND;

    for (int e = t; e < 8192; e += 256) {
        const int i = e >> 6, k = e & 63;
        Ql[i * 65 + k] = Qg[e];
        Kl[i * 65 + k] = Kg[e];
    }
    __syncthreads();

    // scores: 8x8 register tile per thread
    {
        const int i0 = (t >> 4) * 8;
        const int j0 = (t & 15) * 8;
        float s[8][8];
        #pragma unroll
        for (int rr = 0; rr < 8; ++rr)
            #pragma unroll
            for (int cc = 0; cc < 8; ++cc) s[rr][cc] = 0.f;
        for (int k = 0; k < 64; ++k) {
            float qv[8], kv[8];
            #pragma unroll
            for (int rr = 0; rr < 8; ++rr) qv[rr] = Ql[(i0 + rr) * 65 + k];
            #pragma unroll
            for (int cc = 0; cc < 8; ++cc) kv[cc] = Kl[(j0 + cc) * 65 + k];
            #pragma unroll
            for (int rr = 0; rr < 8; ++rr)
                #pragma unroll
                for (int cc = 0; cc < 8; ++cc)
                    s[rr][cc] = fmaf(qv[rr], kv[cc], s[rr][cc]);
        }
        #pragma unroll
        for (int rr = 0; rr < 8; ++rr)
            #pragma unroll
            for (int cc = 0; cc < 8; ++cc)
                Sc[(i0 + rr) * 129 + (j0 + cc)] = s[rr][cc];
    }
    __syncthreads();

    // V fill (Q dead) + per-column partial max; column j, half h
    const int j = t & 127, h = t >> 7;
    {
        for (int e = t; e < 8192; e += 256) {
            const int i = e >> 6, k = e & 63;
            Ql[i * 65 + k] = Vg[e];
        }
        float m = -3.0e38f;
        for (int i = h * 64; i < h * 64 + 64; ++i)
            m = fmaxf(m, Sc[i * 129 + j]);
        Pm[h * 128 + j] = m;
    }
    __syncthreads();
    {
        const float m = fmaxf(Pm[j], Pm[128 + j]);
        float sum = 0.f;
        for (int i = h * 64; i < h * 64 + 64; ++i) {
            const float e = __expf(Sc[i * 129 + j] - m);
            Sc[i * 129 + j] = e;
            sum += e;
        }
        Ps[h * 128 + j] = sum;
    }
    __syncthreads();
    if (t < 128) Rden[t] = 1.0f / (Ps[t] + Ps[128 + t]);
    __syncthreads();

    // PV: 8 rows x 4 cols per thread
    {
        const int i0 = (t >> 4) * 8;
        const int k0 = (t & 15) * 4;
        float z[8][4];
        #pragma unroll
        for (int rr = 0; rr < 8; ++rr)
            #pragma unroll
            for (int cc = 0; cc < 4; ++cc) z[rr][cc] = 0.f;
        for (int jj = 0; jj < 128; ++jj) {
            const float rd = Rden[jj];
            float av[8], vv[4];
            #pragma unroll
            for (int rr = 0; rr < 8; ++rr) av[rr] = Sc[(i0 + rr) * 129 + jj] * rd;
            #pragma unroll
            for (int cc = 0; cc < 4; ++cc) vv[cc] = Ql[jj * 65 + k0 + cc];
            #pragma unroll
            for (int rr = 0; rr < 8; ++rr)
                #pragma unroll
                for (int cc = 0; cc < 4; ++cc)
                    z[rr][cc] = fmaf(av[rr], vv[cc], z[rr][cc]);
        }
        float* op = out + (size_t)b * (SEQ * QKVD) + (size_t)(g * 128) * QKVD + k0;
        #pragma unroll
        for (int rr = 0; rr < 8; ++rr) {
            float4 o;
            o.x = z[rr][0] * 0.125f; o.y = z[rr][1] * 0.125f;
            o.z = z[rr][2] * 0.125f; o.w = z[rr][3] * 0.125f;
            *reinterpret_cast<float4*>(op + (size_t)(i0 + rr) * QKVD) = o;
        }
    }
}

// ---------------- launcher --------------------------------------------------
extern "C" void kernel_launch(void* const* d_in, const int* in_sizes, int n_in,
                              void* d_out, int out_size, void* d_ws, size_t ws_size,
                              hipStream_t stream) {
    const float* x = (const float*)d_in[0];
    WArgs wa;
    for (int g = 0; g < 2; ++g)
        for (int q = 0; q < 3; ++q) {
            wa.W[g * 3 + q] = (const float*)d_in[1 + g * 6 + q * 2];
            wa.b[g * 3 + q] = (const float*)d_in[2 + g * 6 + q * 2];
        }

    short* xb  = (short*)d_ws;                                      // 2 MiB
    float* qkv = (float*)((char*)d_ws + (size_t)4 * 1024 * 1024);   // 12.6 MiB

    cvt_x_kernel<<<dim3(1024), dim3(256), 0, stream>>>(x, xb);
    qkv_gemm_kernel<<<dim3(768), dim3(256), 0, stream>>>(xb, wa, qkv);
    attn_kernel<<<dim3(BATCH, 2), dim3(256), 0, stream>>>(qkv, (float*)d_out);
}